// Round 10
// baseline (436.261 us; speedup 1.0000x reference)
//
#include <hip/hip_runtime.h>
#include <hip/hip_bf16.h>

#define D_HID 32
#define D_IN 128
#define NEG 0.2f
#define BSH 7          // log2 bucket size
#define BSZ 128        // dst nodes per bucket
#define MAXB 1024      // max buckets (N <= 131072)

typedef unsigned short u16;

__device__ __forceinline__ float b2f(u16 u){
  union { unsigned int i; float f; } c; c.i = ((unsigned int)u) << 16; return c.f;
}

__device__ __forceinline__ float ldf(const void* __restrict__ p, int f32, long long i){
  return f32 ? ((const float*)p)[i] : b2f(((const u16*)p)[i]);
}

__device__ __forceinline__ int atomAddI(int* p, int v){
  return __hip_atomic_fetch_add(p, v, __ATOMIC_RELAXED, __HIP_MEMORY_SCOPE_AGENT);
}

// flags[0]: edge_index is int64-layout. flags[1]: float inputs are fp32.
__global__ void detect_flags(const int* __restrict__ ei, const u16* __restrict__ xw,
                             int* __restrict__ flags){
  __shared__ int insane_s, nz_s;
  int t = threadIdx.x;
  if (t == 0){ insane_s = 0; nz_s = 0; }
  __syncthreads();
  int pred = (t < 64) ? (ei[2*t+1] != 0) : 0;
  int e = (xw[t] >> 7) & 0xFF;
  int bad = (e < 100 || e > 140) ? 1 : 0;
  #pragma unroll
  for (int off = 32; off >= 1; off >>= 1){
    bad  += __shfl_down(bad,  off, 64);
    pred += __shfl_down(pred, off, 64);
  }
  if ((t & 63) == 0){
    atomicAdd(&insane_s, bad);
    atomicAdd(&nz_s, pred);
  }
  __syncthreads();
  if (t == 0){
    flags[0] = (nz_s == 0) ? 1 : 0;
    flags[1] = (insane_s > 16) ? 1 : 0;
  }
}

__device__ __forceinline__ void edge_nodes(const int* __restrict__ ei, int E_, int is64,
                                           int e, int& src, int& dst){
  if (is64){ src = ei[2*e]; dst = ei[2*E_ + 2*e]; }
  else     { src = ei[e];   dst = ei[E_ + e]; }
}

// ---------------- node transform (fp32-exact, verified r7) ----------------
template<int K>
__global__ void node_gemm(const void* __restrict__ X,
                          const void* __restrict__ Wl,
                          const void* __restrict__ Wr,
                          const int* __restrict__ flags, int force_f32,
                          float* __restrict__ xl, float* __restrict__ xr, int N_)
{
  int n = blockIdx.x * blockDim.x + threadIdx.x;
  if (n >= N_) return;
  int f32 = force_f32 | flags[1];
  float accl[32], accr[32];
  #pragma unroll
  for (int c = 0; c < 32; ++c){ accl[c] = 0.f; accr[c] = 0.f; }

  if (f32){
    const float* xrow = (const float*)X + (size_t)n * K;
    const float* wl = (const float*)Wl;
    const float* wr = (const float*)Wr;
    for (int k0 = 0; k0 < K; k0 += 4){
      float4 xv = *(const float4*)(xrow + k0);
      #pragma unroll
      for (int kk = 0; kk < 4; ++kk){
        float xs = kk==0 ? xv.x : kk==1 ? xv.y : kk==2 ? xv.z : xv.w;
        int k = k0 + kk;
        #pragma unroll
        for (int c = 0; c < 32; c += 4){
          float4 wl4 = *(const float4*)(wl + k*D_HID + c);
          float4 wr4 = *(const float4*)(wr + k*D_HID + c);
          accl[c+0] = fmaf(xs, wl4.x, accl[c+0]);
          accl[c+1] = fmaf(xs, wl4.y, accl[c+1]);
          accl[c+2] = fmaf(xs, wl4.z, accl[c+2]);
          accl[c+3] = fmaf(xs, wl4.w, accl[c+3]);
          accr[c+0] = fmaf(xs, wr4.x, accr[c+0]);
          accr[c+1] = fmaf(xs, wr4.y, accr[c+1]);
          accr[c+2] = fmaf(xs, wr4.z, accr[c+2]);
          accr[c+3] = fmaf(xs, wr4.w, accr[c+3]);
        }
      }
    }
  } else {
    for (int k = 0; k < K; ++k){
      float xs = ldf(X, 0, (long long)n*K + k);
      #pragma unroll
      for (int c = 0; c < 32; ++c){
        accl[c] = fmaf(xs, ldf(Wl, 0, k*D_HID + c), accl[c]);
        accr[c] = fmaf(xs, ldf(Wr, 0, k*D_HID + c), accr[c]);
      }
    }
  }

  float* lo = xl + (size_t)n * D_HID;
  float* ro = xr + (size_t)n * D_HID;
  #pragma unroll
  for (int c = 0; c < 32; c += 4){
    *(float4*)(lo + c) = make_float4(accl[c], accl[c+1], accl[c+2], accl[c+3]);
    *(float4*)(ro + c) = make_float4(accr[c], accr[c+1], accr[c+2], accr[c+3]);
  }
}

// ---------------- bucket count (LDS histogram, verified r8) ----------------
__global__ void bucket_count(const int* __restrict__ ei, const int* __restrict__ flags,
                             int* __restrict__ gcnt, int E_, int B_){
  __shared__ int hist[MAXB];
  for (int i = threadIdx.x; i < B_; i += 256) hist[i] = 0;
  __syncthreads();
  int chunk = (E_ + gridDim.x - 1) / gridDim.x;
  int s = blockIdx.x * chunk;
  int e = s + chunk; if (e > E_) e = E_;
  int is64 = flags[0];
  for (int i = s + (int)threadIdx.x; i < e; i += 256){
    int dst = is64 ? ei[2*E_ + 2*i] : ei[E_ + i];
    atomicAdd(&hist[dst >> BSH], 1);
  }
  __syncthreads();
  for (int i = threadIdx.x; i < B_; i += 256)
    if (hist[i]) (void)atomAddI(&gcnt[i], hist[i]);
}

// ---------------- exclusive scan over bucket counts (verified r8) ----------------
__global__ void scan_buckets(const int* __restrict__ gcnt, int* __restrict__ offsets,
                             int* __restrict__ cursor, int B_){
  __shared__ int sd[1024];
  int t = threadIdx.x;
  int v = (t < B_) ? gcnt[t] : 0;
  sd[t] = v;
  __syncthreads();
  for (int off = 1; off < 1024; off <<= 1){
    int tmp = (t >= off) ? sd[t-off] : 0;
    __syncthreads();
    sd[t] += tmp;
    __syncthreads();
  }
  if (t < B_){
    int excl = sd[t] - v;
    offsets[t] = excl;
    cursor[t]  = excl;
    if (t == B_-1) offsets[B_] = sd[t];
  }
}

// ---------------- bucket scatter with per-block range reservation (verified r8) ---
__global__ void bucket_scatter(const int* __restrict__ ei, const int* __restrict__ flags,
                               int* __restrict__ cursor, unsigned* __restrict__ seg,
                               int E_, int B_){
  __shared__ int hist[MAXB];
  __shared__ int bbase[MAXB];
  for (int i = threadIdx.x; i < B_; i += 256) hist[i] = 0;
  __syncthreads();
  int chunk = (E_ + gridDim.x - 1) / gridDim.x;
  int s = blockIdx.x * chunk;
  int e = s + chunk; if (e > E_) e = E_;
  int is64 = flags[0];
  for (int i = s + (int)threadIdx.x; i < e; i += 256){
    int dst = is64 ? ei[2*E_ + 2*i] : ei[E_ + i];
    atomicAdd(&hist[dst >> BSH], 1);
  }
  __syncthreads();
  for (int i = threadIdx.x; i < B_; i += 256){
    int c = hist[i];
    bbase[i] = c ? atomAddI(&cursor[i], c) : 0;
  }
  __syncthreads();
  for (int i = threadIdx.x; i < B_; i += 256) hist[i] = 0;  // reuse as local offset
  __syncthreads();
  for (int i = s + (int)threadIdx.x; i < e; i += 256){
    int src, dst;
    edge_nodes(ei, E_, is64, i, src, dst);
    int b = dst >> BSH;
    int pos = bbase[b] + atomicAdd(&hist[b], 1);
    seg[pos] = ((unsigned)src << BSH) | (unsigned)(dst & (BSZ-1));
  }
}

// ---------------- bucket finalize: exact per-dst CSR (+ per-edge dst array) -------
__global__ void bucket_finalize(const unsigned* __restrict__ seg,
                                const int* __restrict__ offsets,
                                int* __restrict__ row, int* __restrict__ csr_src,
                                int* __restrict__ csr_dst,
                                int N_, int B_){
  __shared__ int hist[BSZ];
  __shared__ int sc[BSZ];
  __shared__ int loff[BSZ];
  int b = blockIdx.x;
  int t = threadIdx.x;
  int base = offsets[b], cnt = offsets[b+1] - base;
  if (t < BSZ) hist[t] = 0;
  __syncthreads();
  for (int i = t; i < cnt; i += 256)
    atomicAdd(&hist[seg[base+i] & (BSZ-1)], 1);
  __syncthreads();
  if (t < BSZ) sc[t] = hist[t];
  __syncthreads();
  for (int off = 1; off < BSZ; off <<= 1){
    int tmp = (t < BSZ && t >= off) ? sc[t-off] : 0;
    __syncthreads();
    if (t < BSZ) sc[t] += tmp;
    __syncthreads();
  }
  if (t < BSZ){
    int excl = sc[t] - hist[t];
    loff[t] = excl;
    int node = b*BSZ + t;
    if (node <= N_) row[node] = base + excl;
  }
  if (b == B_-1 && t == 0) row[N_] = offsets[B_];
  __syncthreads();
  for (int i = t; i < cnt; i += 256){
    unsigned en = seg[base+i];
    int dl = en & (BSZ-1);
    int pos = atomicAdd(&loff[dl], 1);
    csr_src[base + pos] = (int)(en >> BSH);
    csr_dst[base + pos] = b*BSZ + dl;
  }
}

// ---------------- pass A: per-edge attention weight (no shuffles) ----------------
// Thread per edge in CSR order. In-lane 32-wide dot; xr[dst] loads are L1-hot
// (dst sorted); att is wave-uniform -> scalar regs. ex[e] = exp(logit).
__global__ void edge_logit(const int* __restrict__ csr_src, const int* __restrict__ csr_dst,
                           const float* __restrict__ xl, const float* __restrict__ xr,
                           const void* __restrict__ att, const int* __restrict__ flags,
                           float* __restrict__ ex, int E_)
{
  int e = blockIdx.x * blockDim.x + threadIdx.x;
  if (e >= E_) return;
  int f32 = flags[1];
  int src = csr_src[e], dst = csr_dst[e];
  const float4* a = (const float4*)(xl + (size_t)src * D_HID);
  const float4* b = (const float4*)(xr + (size_t)dst * D_HID);
  float logit = 0.f;
  #pragma unroll
  for (int q = 0; q < 8; ++q){
    float4 av = a[q], bv = b[q];
    float h0 = av.x + bv.x; h0 = h0 > 0.f ? h0 : NEG*h0;
    float h1 = av.y + bv.y; h1 = h1 > 0.f ? h1 : NEG*h1;
    float h2 = av.z + bv.z; h2 = h2 > 0.f ? h2 : NEG*h2;
    float h3 = av.w + bv.w; h3 = h3 > 0.f ? h3 : NEG*h3;
    logit = fmaf(h0, ldf(att, f32, q*4+0), logit);
    logit = fmaf(h1, ldf(att, f32, q*4+1), logit);
    logit = fmaf(h2, ldf(att, f32, q*4+2), logit);
    logit = fmaf(h3, ldf(att, f32, q*4+3), logit);
  }
  logit = fminf(logit, 60.f);    // safety clamp; real logits |.| <~ 15
  ex[e] = __expf(logit);
}

// ---------------- pass B: per-dst weighted aggregate (no per-edge shuffles) ------
// Wave per dst; half-wave owns 4 consecutive edges per iteration; lane k of 32
// owns feature k. ev is a broadcast load; every lane redundantly sums ssum, so
// the only cross-lane op is the final half-combine.
__global__ void gat_aggr(const int* __restrict__ row, const int* __restrict__ csr_src,
                         const float* __restrict__ ex,
                         const float* __restrict__ xl,
                         const void* __restrict__ bias, const int* __restrict__ flags,
                         float* __restrict__ outp, int N_, int do_relu)
{
  int n = blockIdx.x * (blockDim.x >> 6) + (threadIdx.x >> 6);
  if (n >= N_) return;
  int lane = threadIdx.x & 63;
  int half = lane >> 5, k = lane & 31;
  int f32 = flags[1];
  int rs = row[n], re = row[n+1];
  float acc = 0.f, ssum = 0.f;
  for (int i0 = rs + 4*half; i0 < re; i0 += 8){   // this half's edges: i0..i0+3
    float xlv[4], evv[4];
    int valid[4];
    #pragma unroll
    for (int u = 0; u < 4; ++u){
      int i = i0 + u;
      valid[u] = (i < re);
      int ic = valid[u] ? i : (re - 1);            // clamped: always-legal address
      int src = csr_src[ic];
      evv[u] = ex[ic];
      xlv[u] = xl[(size_t)src*D_HID + k];
    }
    #pragma unroll
    for (int u = 0; u < 4; ++u){
      if (valid[u]){                               // uniform within the half-wave
        ssum += evv[u];
        acc = fmaf(evv[u], xlv[u], acc);
      }
    }
  }
  // combine the two half-wave partial sums (lane^32 has same k)
  acc  += __shfl_xor(acc, 32, 64);
  ssum += __shfl_xor(ssum, 32, 64);
  if (half == 0){
    float v = acc / (ssum + 1e-16f) + ldf(bias, f32, k);
    if (do_relu) v = v > 0.f ? v : 0.f;
    outp[(size_t)n*D_HID + k] = v;
  }
}

extern "C" void kernel_launch(void* const* d_in, const int* in_sizes, int n_in,
                              void* d_out, int out_size, void* d_ws, size_t ws_size,
                              hipStream_t stream)
{
  const void* x   = d_in[0];
  const int*  ei  = (const int*)d_in[1];
  const void* W1l = d_in[2];
  const void* W1r = d_in[3];
  const void* att1= d_in[4];
  const void* b1  = d_in[5];
  const void* W2l = d_in[6];
  const void* W2r = d_in[7];
  const void* att2= d_in[8];
  const void* b2  = d_in[9];
  float* out = (float*)d_out;

  int N_ = in_sizes[0] / D_IN;
  int E_ = in_sizes[1] / 2;
  int B_ = (N_ + BSZ - 1) / BSZ;

  char* ws = (char*)d_ws;
  size_t off = 0;
  auto carve = [&](size_t bytes) -> char* {
    char* p = ws + off;
    off += (bytes + 255) & ~(size_t)255;
    return p;
  };
  float*    xl      = (float*)   carve((size_t)N_ * D_HID * 4);
  float*    xr      = (float*)   carve((size_t)N_ * D_HID * 4);
  float*    h       = (float*)   carve((size_t)N_ * D_HID * 4);
  unsigned* seg     = (unsigned*)carve((size_t)E_ * 4);  // dead after finalize; ex aliases it
  int*      csr_src = (int*)     carve((size_t)E_ * 4);
  int*      csr_dst = (int*)     carve((size_t)E_ * 4);
  int*      row     = (int*)     carve((size_t)(N_ + 1) * 4);
  int*      offsets = (int*)     carve((size_t)(MAXB + 1) * 4);
  int*      gcnt    = (int*)     carve((size_t)MAXB * 4);
  int*      cursor  = (int*)     carve((size_t)MAXB * 4);
  int*      flags   = (int*)     carve(256);
  float*    ex      = (float*)seg;                       // alias (seg dead by then)

  const int tpb = 256;
  int gN = (N_ + tpb - 1) / tpb;
  int gE = (E_ + tpb - 1) / tpb;
  int gW = (N_ + 3) / 4;                    // wave-per-dst grid (4 waves/block)

  detect_flags<<<1, 256, 0, stream>>>(ei, (const u16*)x, flags);

  // ---- CSR build (shared by both layers) ----
  hipMemsetAsync(gcnt, 0, (size_t)MAXB * 4, stream);
  bucket_count<<<256, tpb, 0, stream>>>(ei, flags, gcnt, E_, B_);
  scan_buckets<<<1, 1024, 0, stream>>>(gcnt, offsets, cursor, B_);
  bucket_scatter<<<256, tpb, 0, stream>>>(ei, flags, cursor, seg, E_, B_);
  bucket_finalize<<<B_, tpb, 0, stream>>>(seg, offsets, row, csr_src, csr_dst, N_, B_);

  // ---- layer 1 ----
  node_gemm<D_IN><<<gN, tpb, 0, stream>>>(x, W1l, W1r, flags, 0, xl, xr, N_);
  edge_logit<<<gE, tpb, 0, stream>>>(csr_src, csr_dst, xl, xr, att1, flags, ex, E_);
  gat_aggr<<<gW, tpb, 0, stream>>>(row, csr_src, ex, xl, b1, flags, h, N_, 1);

  // ---- layer 2 ----
  node_gemm<D_HID><<<gN, tpb, 0, stream>>>(h, W2l, W2r, flags, 1, xl, xr, N_);
  edge_logit<<<gE, tpb, 0, stream>>>(csr_src, csr_dst, xl, xr, att2, flags, ex, E_);
  gat_aggr<<<gW, tpb, 0, stream>>>(row, csr_src, ex, xl, b2, flags, out, N_, 0);
}

// Round 11
// 349.111 us; speedup vs baseline: 1.2496x; 1.2496x over previous
//
#include <hip/hip_runtime.h>
#include <hip/hip_bf16.h>

#define D_HID 32
#define D_IN 128
#define NEG 0.2f
#define BSH 7          // log2 bucket size
#define BSZ 128        // dst nodes per bucket
#define MAXB 1024      // max buckets (N <= 131072)

typedef unsigned short u16;
typedef __attribute__((ext_vector_type(8))) short short8;   // 8 bf16 (4 VGPRs)
typedef __attribute__((ext_vector_type(4))) float float4v;  // 4 fp32 acc

__device__ __forceinline__ float b2f(u16 u){
  union { unsigned int i; float f; } c; c.i = ((unsigned int)u) << 16; return c.f;
}

__device__ __forceinline__ u16 f2b_rne(float f){
  union { float f; unsigned int u; } c; c.f = f;
  unsigned int u = c.u;
  return (u16)((u + 0x7FFFu + ((u >> 16) & 1u)) >> 16);
}

// fp32 -> bf16 hi + bf16 lo (captures ~16 mantissa bits)
__device__ __forceinline__ void split_bf16(float v, u16& hi, u16& lo){
  hi = f2b_rne(v);
  lo = f2b_rne(v - b2f(hi));
}

__device__ __forceinline__ float ldf(const void* __restrict__ p, int f32, long long i){
  return f32 ? ((const float*)p)[i] : b2f(((const u16*)p)[i]);
}

__device__ __forceinline__ int atomAddI(int* p, int v){
  return __hip_atomic_fetch_add(p, v, __ATOMIC_RELAXED, __HIP_MEMORY_SCOPE_AGENT);
}

// flags[0]: edge_index is int64-layout. flags[1]: float inputs are fp32.
__global__ void detect_flags(const int* __restrict__ ei, const u16* __restrict__ xw,
                             int* __restrict__ flags){
  __shared__ int insane_s, nz_s;
  int t = threadIdx.x;
  if (t == 0){ insane_s = 0; nz_s = 0; }
  __syncthreads();
  int pred = (t < 64) ? (ei[2*t+1] != 0) : 0;
  int e = (xw[t] >> 7) & 0xFF;
  int bad = (e < 100 || e > 140) ? 1 : 0;
  #pragma unroll
  for (int off = 32; off >= 1; off >>= 1){
    bad  += __shfl_down(bad,  off, 64);
    pred += __shfl_down(pred, off, 64);
  }
  if ((t & 63) == 0){
    atomicAdd(&insane_s, bad);
    atomicAdd(&nz_s, pred);
  }
  __syncthreads();
  if (t == 0){
    flags[0] = (nz_s == 0) ? 1 : 0;
    flags[1] = (insane_s > 16) ? 1 : 0;
  }
}

__device__ __forceinline__ void edge_nodes(const int* __restrict__ ei, int E_, int is64,
                                           int e, int& src, int& dst){
  if (is64){ src = ei[2*e]; dst = ei[2*E_ + 2*e]; }
  else     { src = ei[e];   dst = ei[E_ + e]; }
}

// ---------------- W-fragment precompute ----------------
// B-operand layout for mfma_f32_16x16x32_bf16: lane holds B[k=quad*8+j][n=lane&15].
// Entry index rem = ctile*KS + kstep; 64 lanes per entry; uint4 = 8 bf16.
__global__ void prep_wfrag(const void* __restrict__ Wl, const void* __restrict__ Wr,
                           const int* __restrict__ flags, int K,
                           uint4* __restrict__ whi, uint4* __restrict__ wlo){
  int t = blockIdx.x * blockDim.x + threadIdx.x;
  int KS = K >> 5;
  int total = 4 * KS * 64;
  if (t >= total) return;
  int lane = t & 63;
  int rem = t >> 6;            // ctile*KS + kstep
  int kstep = rem % KS;
  int ctile = rem / KS;
  int f32 = flags[1];
  int col = ctile * 16 + (lane & 15);   // output col in [0,64): 0-31 -> Wl, 32-63 -> Wr
  int quad = lane >> 4;
  union { u16 s[8]; uint4 q; } ch, cl;
  #pragma unroll
  for (int j = 0; j < 8; ++j){
    int k = kstep*32 + quad*8 + j;
    float v = (col < 32) ? ldf(Wl, f32, (long long)k*D_HID + col)
                         : ldf(Wr, f32, (long long)k*D_HID + (col - 32));
    u16 hi, lo; split_bf16(v, hi, lo);
    ch.s[j] = hi; cl.s[j] = lo;
  }
  whi[rem*64 + lane] = ch.q;
  wlo[rem*64 + lane] = cl.q;
}

// ---------------- MFMA node transform (split-bf16, 3 MFMAs / k-step) -------------
// C = X[N x K] @ [Wl | Wr][K x 64]. One wave per 16 nodes; 4 col-tiles of 16.
// A layout: A[m=lane&15][k=quad*8+j]; C/D: col=lane&15, row=quad*4+reg (verified
// guide mappings, m89/m120).
template<int K>
__global__ void mfma_gemm(const void* __restrict__ X,
                          const uint4* __restrict__ whi, const uint4* __restrict__ wlo,
                          const int* __restrict__ flags, int force_f32,
                          float* __restrict__ xl, float* __restrict__ xr, int N_)
{
  constexpr int KS = K >> 5;
  int tile = blockIdx.x * (blockDim.x >> 6) + (threadIdx.x >> 6);
  if (tile * 16 >= N_) return;
  int lane = threadIdx.x & 63;
  int quad = lane >> 4;
  int m = tile*16 + (lane & 15);
  if (m >= N_) m = N_ - 1;             // tail-safe loads (stores guarded)
  int f32 = force_f32 | flags[1];

  float4v acc[4];
  #pragma unroll
  for (int c = 0; c < 4; ++c) acc[c] = (float4v){0.f,0.f,0.f,0.f};

  #pragma unroll
  for (int ks = 0; ks < KS; ++ks){
    long long base = (long long)m * K + ks*32 + quad*8;
    float av[8];
    if (f32){
      const float4* xp = (const float4*)((const float*)X + base);
      float4 t0 = xp[0], t1 = xp[1];
      av[0]=t0.x; av[1]=t0.y; av[2]=t0.z; av[3]=t0.w;
      av[4]=t1.x; av[5]=t1.y; av[6]=t1.z; av[7]=t1.w;
    } else {
      union { uint4 q; u16 s[8]; } c8;
      c8.q = *(const uint4*)((const u16*)X + base);
      #pragma unroll
      for (int j = 0; j < 8; ++j) av[j] = b2f(c8.s[j]);
    }
    short8 ahi, alo;
    #pragma unroll
    for (int j = 0; j < 8; ++j){
      u16 hi, lo; split_bf16(av[j], hi, lo);
      ahi[j] = (short)hi; alo[j] = (short)lo;
    }
    #pragma unroll
    for (int c = 0; c < 4; ++c){
      uint4 wh = whi[(c*KS + ks)*64 + lane];
      uint4 wl = wlo[(c*KS + ks)*64 + lane];
      short8 bh = *(short8*)&wh;
      short8 bl = *(short8*)&wl;
      acc[c] = __builtin_amdgcn_mfma_f32_16x16x32_bf16(ahi, bh, acc[c], 0, 0, 0);
      acc[c] = __builtin_amdgcn_mfma_f32_16x16x32_bf16(ahi, bl, acc[c], 0, 0, 0);
      acc[c] = __builtin_amdgcn_mfma_f32_16x16x32_bf16(alo, bh, acc[c], 0, 0, 0);
    }
  }

  #pragma unroll
  for (int c = 0; c < 4; ++c){
    int col = c*16 + (lane & 15);
    float* dst = (col < 32) ? xl : xr;
    int kk = col & 31;
    #pragma unroll
    for (int r = 0; r < 4; ++r){
      int node = tile*16 + quad*4 + r;
      if (node < N_) dst[(size_t)node*D_HID + kk] = acc[c][r];
    }
  }
}

// ---------------- bucket count (LDS histogram, verified r8) ----------------
__global__ void bucket_count(const int* __restrict__ ei, const int* __restrict__ flags,
                             int* __restrict__ gcnt, int E_, int B_){
  __shared__ int hist[MAXB];
  for (int i = threadIdx.x; i < B_; i += 256) hist[i] = 0;
  __syncthreads();
  int chunk = (E_ + gridDim.x - 1) / gridDim.x;
  int s = blockIdx.x * chunk;
  int e = s + chunk; if (e > E_) e = E_;
  int is64 = flags[0];
  for (int i = s + (int)threadIdx.x; i < e; i += 256){
    int dst = is64 ? ei[2*E_ + 2*i] : ei[E_ + i];
    atomicAdd(&hist[dst >> BSH], 1);
  }
  __syncthreads();
  for (int i = threadIdx.x; i < B_; i += 256)
    if (hist[i]) (void)atomAddI(&gcnt[i], hist[i]);
}

// ---------------- exclusive scan over bucket counts (verified r8) ----------------
__global__ void scan_buckets(const int* __restrict__ gcnt, int* __restrict__ offsets,
                             int* __restrict__ cursor, int B_){
  __shared__ int sd[1024];
  int t = threadIdx.x;
  int v = (t < B_) ? gcnt[t] : 0;
  sd[t] = v;
  __syncthreads();
  for (int off = 1; off < 1024; off <<= 1){
    int tmp = (t >= off) ? sd[t-off] : 0;
    __syncthreads();
    sd[t] += tmp;
    __syncthreads();
  }
  if (t < B_){
    int excl = sd[t] - v;
    offsets[t] = excl;
    cursor[t]  = excl;
    if (t == B_-1) offsets[B_] = sd[t];
  }
}

// ---------------- bucket scatter with per-block range reservation (verified r8) ---
__global__ void bucket_scatter(const int* __restrict__ ei, const int* __restrict__ flags,
                               int* __restrict__ cursor, unsigned* __restrict__ seg,
                               int E_, int B_){
  __shared__ int hist[MAXB];
  __shared__ int bbase[MAXB];
  for (int i = threadIdx.x; i < B_; i += 256) hist[i] = 0;
  __syncthreads();
  int chunk = (E_ + gridDim.x - 1) / gridDim.x;
  int s = blockIdx.x * chunk;
  int e = s + chunk; if (e > E_) e = E_;
  int is64 = flags[0];
  for (int i = s + (int)threadIdx.x; i < e; i += 256){
    int dst = is64 ? ei[2*E_ + 2*i] : ei[E_ + i];
    atomicAdd(&hist[dst >> BSH], 1);
  }
  __syncthreads();
  for (int i = threadIdx.x; i < B_; i += 256){
    int c = hist[i];
    bbase[i] = c ? atomAddI(&cursor[i], c) : 0;
  }
  __syncthreads();
  for (int i = threadIdx.x; i < B_; i += 256) hist[i] = 0;  // reuse as local offset
  __syncthreads();
  for (int i = s + (int)threadIdx.x; i < e; i += 256){
    int src, dst;
    edge_nodes(ei, E_, is64, i, src, dst);
    int b = dst >> BSH;
    int pos = bbase[b] + atomicAdd(&hist[b], 1);
    seg[pos] = ((unsigned)src << BSH) | (unsigned)(dst & (BSZ-1));
  }
}

// ---------------- bucket finalize: exact per-dst CSR (verified r9) ----------------
__global__ void bucket_finalize(const unsigned* __restrict__ seg,
                                const int* __restrict__ offsets,
                                int* __restrict__ row, int* __restrict__ csr_src,
                                int N_, int B_){
  __shared__ int hist[BSZ];
  __shared__ int sc[BSZ];
  __shared__ int loff[BSZ];
  int b = blockIdx.x;
  int t = threadIdx.x;
  int base = offsets[b], cnt = offsets[b+1] - base;
  if (t < BSZ) hist[t] = 0;
  __syncthreads();
  for (int i = t; i < cnt; i += 256)
    atomicAdd(&hist[seg[base+i] & (BSZ-1)], 1);
  __syncthreads();
  if (t < BSZ) sc[t] = hist[t];
  __syncthreads();
  for (int off = 1; off < BSZ; off <<= 1){
    int tmp = (t < BSZ && t >= off) ? sc[t-off] : 0;
    __syncthreads();
    if (t < BSZ) sc[t] += tmp;
    __syncthreads();
  }
  if (t < BSZ){
    int excl = sc[t] - hist[t];
    loff[t] = excl;
    int node = b*BSZ + t;
    if (node <= N_) row[node] = base + excl;
  }
  if (b == B_-1 && t == 0) row[N_] = offsets[B_];
  __syncthreads();
  for (int i = t; i < cnt; i += 256){
    unsigned en = seg[base+i];
    int dl = en & (BSZ-1);
    int pos = atomicAdd(&loff[dl], 1);
    csr_src[base + pos] = (int)(en >> BSH);
  }
}

// ---------------- fused per-dst gather (verified r9, byte-identical) --------------
__global__ void gat_gather(const int* __restrict__ row, const int* __restrict__ csr_src,
                           const float* __restrict__ xl, const float* __restrict__ xr,
                           const void* __restrict__ att, const void* __restrict__ bias,
                           const int* __restrict__ flags,
                           float* __restrict__ outp, int N_, int do_relu)
{
  int n = blockIdx.x * (blockDim.x >> 6) + (threadIdx.x >> 6);
  if (n >= N_) return;
  int lane = threadIdx.x & 63;
  int half = lane >> 5, k = lane & 31;
  int f32 = flags[1];
  float attk = ldf(att, f32, k);
  float xrk = xr[(size_t)n*D_HID + k];
  int rs = row[n], re = row[n+1];
  float acc = 0.f, ssum = 0.f;
  for (int i0 = rs + half; i0 < re; i0 += 8){   // this half's edges: i0+{0,2,4,6}
    float xlv[4];
    int valid[4];
    #pragma unroll
    for (int u = 0; u < 4; ++u){
      int i = i0 + 2*u;
      valid[u] = (i < re);
      int ic = valid[u] ? i : (re - 1);          // clamped: always-legal address
      int src = csr_src[ic];
      xlv[u] = xl[(size_t)src*D_HID + k];
    }
    #pragma unroll
    for (int u = 0; u < 4; ++u){
      if (valid[u]){                             // uniform within the half-wave
        float h = xlv[u] + xrk;
        h = h > 0.f ? h : NEG*h;
        float p = h * attk;
        p += __shfl_xor(p, 16, 32);
        p += __shfl_xor(p,  8, 32);
        p += __shfl_xor(p,  4, 32);
        p += __shfl_xor(p,  2, 32);
        p += __shfl_xor(p,  1, 32);
        p = fminf(p, 60.f);                      // safety clamp; real logits |.| <~ 15
        float ev = __expf(p);
        ssum += ev;
        acc = fmaf(ev, xlv[u], acc);
      }
    }
  }
  // combine the two half-wave partial sums (lane^32 has same k)
  acc  += __shfl_xor(acc, 32, 64);
  ssum += __shfl_xor(ssum, 32, 64);
  if (half == 0){
    float v = acc / (ssum + 1e-16f) + ldf(bias, f32, k);
    if (do_relu) v = v > 0.f ? v : 0.f;
    outp[(size_t)n*D_HID + k] = v;
  }
}

extern "C" void kernel_launch(void* const* d_in, const int* in_sizes, int n_in,
                              void* d_out, int out_size, void* d_ws, size_t ws_size,
                              hipStream_t stream)
{
  const void* x   = d_in[0];
  const int*  ei  = (const int*)d_in[1];
  const void* W1l = d_in[2];
  const void* W1r = d_in[3];
  const void* att1= d_in[4];
  const void* b1  = d_in[5];
  const void* W2l = d_in[6];
  const void* W2r = d_in[7];
  const void* att2= d_in[8];
  const void* b2  = d_in[9];
  float* out = (float*)d_out;

  int N_ = in_sizes[0] / D_IN;
  int E_ = in_sizes[1] / 2;
  int B_ = (N_ + BSZ - 1) / BSZ;

  char* ws = (char*)d_ws;
  size_t off = 0;
  auto carve = [&](size_t bytes) -> char* {
    char* p = ws + off;
    off += (bytes + 255) & ~(size_t)255;
    return p;
  };
  float*    xl      = (float*)   carve((size_t)N_ * D_HID * 4);
  float*    xr      = (float*)   carve((size_t)N_ * D_HID * 4);
  float*    h       = (float*)   carve((size_t)N_ * D_HID * 4);
  unsigned* seg     = (unsigned*)carve((size_t)E_ * 4);
  int*      csr_src = (int*)     carve((size_t)E_ * 4);
  int*      row     = (int*)     carve((size_t)(N_ + 1) * 4);
  int*      offsets = (int*)     carve((size_t)(MAXB + 1) * 4);
  int*      gcnt    = (int*)     carve((size_t)MAXB * 4);
  int*      cursor  = (int*)     carve((size_t)MAXB * 4);
  int*      flags   = (int*)     carve(256);
  uint4*    whi1    = (uint4*)   carve((size_t)4 * 4 * 64 * 16);  // K=128
  uint4*    wlo1    = (uint4*)   carve((size_t)4 * 4 * 64 * 16);
  uint4*    whi2    = (uint4*)   carve((size_t)4 * 1 * 64 * 16);  // K=32
  uint4*    wlo2    = (uint4*)   carve((size_t)4 * 1 * 64 * 16);

  const int tpb = 256;
  int gW = (N_ + 3) / 4;                    // wave-per-dst grid (4 waves/block)
  int tiles = (N_ + 15) / 16;
  int gT = (tiles + 3) / 4;                 // mfma grid (4 waves/block)

  detect_flags<<<1, 256, 0, stream>>>(ei, (const u16*)x, flags);

  // ---- W fragments ----
  prep_wfrag<<<4, 256, 0, stream>>>(W1l, W1r, flags, D_IN, whi1, wlo1);
  prep_wfrag<<<1, 256, 0, stream>>>(W2l, W2r, flags, D_HID, whi2, wlo2);

  // ---- CSR build (shared by both layers) ----
  hipMemsetAsync(gcnt, 0, (size_t)MAXB * 4, stream);
  bucket_count<<<256, tpb, 0, stream>>>(ei, flags, gcnt, E_, B_);
  scan_buckets<<<1, 1024, 0, stream>>>(gcnt, offsets, cursor, B_);
  bucket_scatter<<<256, tpb, 0, stream>>>(ei, flags, cursor, seg, E_, B_);
  bucket_finalize<<<B_, tpb, 0, stream>>>(seg, offsets, row, csr_src, N_, B_);

  // ---- layer 1 ----
  mfma_gemm<D_IN><<<gT, tpb, 0, stream>>>(x, whi1, wlo1, flags, 0, xl, xr, N_);
  gat_gather<<<gW, tpb, 0, stream>>>(row, csr_src, xl, xr, att1, b1, flags, h, N_, 1);

  // ---- layer 2 ----
  mfma_gemm<D_HID><<<gT, tpb, 0, stream>>>(h, whi2, wlo2, flags, 1, xl, xr, N_);
  gat_gather<<<gW, tpb, 0, stream>>>(row, csr_src, xl, xr, att2, b2, flags, out, N_, 0);
}

// Round 12
// 300.674 us; speedup vs baseline: 1.4509x; 1.1611x over previous
//
#include <hip/hip_runtime.h>
#include <hip/hip_bf16.h>

#define D_HID 32
#define D_IN 128
#define NEG 0.2f
#define BSH 7          // log2 bucket size
#define BSZ 128        // dst nodes per bucket
#define MAXB 1024      // max buckets (N <= 131072)

typedef unsigned short u16;
typedef __attribute__((ext_vector_type(8))) short short8;   // 8 bf16 (4 VGPRs)
typedef __attribute__((ext_vector_type(4))) float float4v;  // 4 fp32 acc

__device__ __forceinline__ float b2f(u16 u){
  union { unsigned int i; float f; } c; c.i = ((unsigned int)u) << 16; return c.f;
}

__device__ __forceinline__ u16 f2b_rne(float f){
  union { float f; unsigned int u; } c; c.f = f;
  unsigned int u = c.u;
  return (u16)((u + 0x7FFFu + ((u >> 16) & 1u)) >> 16);
}

// fp32 -> bf16 hi + bf16 lo (captures ~16 mantissa bits)
__device__ __forceinline__ void split_bf16(float v, u16& hi, u16& lo){
  hi = f2b_rne(v);
  lo = f2b_rne(v - b2f(hi));
}

__device__ __forceinline__ float ldf(const void* __restrict__ p, int f32, long long i){
  return f32 ? ((const float*)p)[i] : b2f(((const u16*)p)[i]);
}

__device__ __forceinline__ int atomAddI(int* p, int v){
  return __hip_atomic_fetch_add(p, v, __ATOMIC_RELAXED, __HIP_MEMORY_SCOPE_AGENT);
}

// flags[0]: edge_index is int64-layout. flags[1]: float inputs are fp32.
__global__ void detect_flags(const int* __restrict__ ei, const u16* __restrict__ xw,
                             int* __restrict__ flags){
  __shared__ int insane_s, nz_s;
  int t = threadIdx.x;
  if (t == 0){ insane_s = 0; nz_s = 0; }
  __syncthreads();
  int pred = (t < 64) ? (ei[2*t+1] != 0) : 0;
  int e = (xw[t] >> 7) & 0xFF;
  int bad = (e < 100 || e > 140) ? 1 : 0;
  #pragma unroll
  for (int off = 32; off >= 1; off >>= 1){
    bad  += __shfl_down(bad,  off, 64);
    pred += __shfl_down(pred, off, 64);
  }
  if ((t & 63) == 0){
    atomicAdd(&insane_s, bad);
    atomicAdd(&nz_s, pred);
  }
  __syncthreads();
  if (t == 0){
    flags[0] = (nz_s == 0) ? 1 : 0;
    flags[1] = (insane_s > 16) ? 1 : 0;
  }
}

__device__ __forceinline__ void edge_nodes(const int* __restrict__ ei, int E_, int is64,
                                           int e, int& src, int& dst){
  if (is64){ src = ei[2*e]; dst = ei[2*E_ + 2*e]; }
  else     { src = ei[e];   dst = ei[E_ + e]; }
}

// ---------------- W-fragment precompute (verified r11) ----------------
__global__ void prep_wfrag(const void* __restrict__ Wl, const void* __restrict__ Wr,
                           const int* __restrict__ flags, int K,
                           uint4* __restrict__ whi, uint4* __restrict__ wlo){
  int t = blockIdx.x * blockDim.x + threadIdx.x;
  int KS = K >> 5;
  int total = 4 * KS * 64;
  if (t >= total) return;
  int lane = t & 63;
  int rem = t >> 6;            // ctile*KS + kstep
  int kstep = rem % KS;
  int ctile = rem / KS;
  int f32 = flags[1];
  int col = ctile * 16 + (lane & 15);
  int quad = lane >> 4;
  union { u16 s[8]; uint4 q; } ch, cl;
  #pragma unroll
  for (int j = 0; j < 8; ++j){
    int k = kstep*32 + quad*8 + j;
    float v = (col < 32) ? ldf(Wl, f32, (long long)k*D_HID + col)
                         : ldf(Wr, f32, (long long)k*D_HID + (col - 32));
    u16 hi, lo; split_bf16(v, hi, lo);
    ch.s[j] = hi; cl.s[j] = lo;
  }
  whi[rem*64 + lane] = ch.q;
  wlo[rem*64 + lane] = cl.q;
}

// ---------------- MFMA node transform (split-bf16, verified r11) -----------------
template<int K>
__global__ void mfma_gemm(const void* __restrict__ X,
                          const uint4* __restrict__ whi, const uint4* __restrict__ wlo,
                          const int* __restrict__ flags, int force_f32,
                          float* __restrict__ xl, float* __restrict__ xr, int N_)
{
  constexpr int KS = K >> 5;
  int tile = blockIdx.x * (blockDim.x >> 6) + (threadIdx.x >> 6);
  if (tile * 16 >= N_) return;
  int lane = threadIdx.x & 63;
  int quad = lane >> 4;
  int m = tile*16 + (lane & 15);
  if (m >= N_) m = N_ - 1;             // tail-safe loads (stores guarded)
  int f32 = force_f32 | flags[1];

  float4v acc[4];
  #pragma unroll
  for (int c = 0; c < 4; ++c) acc[c] = (float4v){0.f,0.f,0.f,0.f};

  #pragma unroll
  for (int ks = 0; ks < KS; ++ks){
    long long base = (long long)m * K + ks*32 + quad*8;
    float av[8];
    if (f32){
      const float4* xp = (const float4*)((const float*)X + base);
      float4 t0 = xp[0], t1 = xp[1];
      av[0]=t0.x; av[1]=t0.y; av[2]=t0.z; av[3]=t0.w;
      av[4]=t1.x; av[5]=t1.y; av[6]=t1.z; av[7]=t1.w;
    } else {
      union { uint4 q; u16 s[8]; } c8;
      c8.q = *(const uint4*)((const u16*)X + base);
      #pragma unroll
      for (int j = 0; j < 8; ++j) av[j] = b2f(c8.s[j]);
    }
    short8 ahi, alo;
    #pragma unroll
    for (int j = 0; j < 8; ++j){
      u16 hi, lo; split_bf16(av[j], hi, lo);
      ahi[j] = (short)hi; alo[j] = (short)lo;
    }
    #pragma unroll
    for (int c = 0; c < 4; ++c){
      uint4 wh = whi[(c*KS + ks)*64 + lane];
      uint4 wl = wlo[(c*KS + ks)*64 + lane];
      short8 bh = *(short8*)&wh;
      short8 bl = *(short8*)&wl;
      acc[c] = __builtin_amdgcn_mfma_f32_16x16x32_bf16(ahi, bh, acc[c], 0, 0, 0);
      acc[c] = __builtin_amdgcn_mfma_f32_16x16x32_bf16(ahi, bl, acc[c], 0, 0, 0);
      acc[c] = __builtin_amdgcn_mfma_f32_16x16x32_bf16(alo, bh, acc[c], 0, 0, 0);
    }
  }

  #pragma unroll
  for (int c = 0; c < 4; ++c){
    int col = c*16 + (lane & 15);
    float* dst = (col < 32) ? xl : xr;
    int kk = col & 31;
    #pragma unroll
    for (int r = 0; r < 4; ++r){
      int node = tile*16 + quad*4 + r;
      if (node < N_) dst[(size_t)node*D_HID + kk] = acc[c][r];
    }
  }
}

// ---------------- bucket count (LDS histogram, verified r8) ----------------
__global__ void bucket_count(const int* __restrict__ ei, const int* __restrict__ flags,
                             int* __restrict__ gcnt, int E_, int B_){
  __shared__ int hist[MAXB];
  for (int i = threadIdx.x; i < B_; i += 256) hist[i] = 0;
  __syncthreads();
  int chunk = (E_ + gridDim.x - 1) / gridDim.x;
  int s = blockIdx.x * chunk;
  int e = s + chunk; if (e > E_) e = E_;
  int is64 = flags[0];
  for (int i = s + (int)threadIdx.x; i < e; i += 256){
    int dst = is64 ? ei[2*E_ + 2*i] : ei[E_ + i];
    atomicAdd(&hist[dst >> BSH], 1);
  }
  __syncthreads();
  for (int i = threadIdx.x; i < B_; i += 256)
    if (hist[i]) (void)atomAddI(&gcnt[i], hist[i]);
}

// ---------------- exclusive scan over bucket counts (verified r8) ----------------
__global__ void scan_buckets(const int* __restrict__ gcnt, int* __restrict__ offsets,
                             int* __restrict__ cursor, int B_){
  __shared__ int sd[1024];
  int t = threadIdx.x;
  int v = (t < B_) ? gcnt[t] : 0;
  sd[t] = v;
  __syncthreads();
  for (int off = 1; off < 1024; off <<= 1){
    int tmp = (t >= off) ? sd[t-off] : 0;
    __syncthreads();
    sd[t] += tmp;
    __syncthreads();
  }
  if (t < B_){
    int excl = sd[t] - v;
    offsets[t] = excl;
    cursor[t]  = excl;
    if (t == B_-1) offsets[B_] = sd[t];
  }
}

// ---------------- bucket scatter with per-block range reservation (verified r8) ---
__global__ void bucket_scatter(const int* __restrict__ ei, const int* __restrict__ flags,
                               int* __restrict__ cursor, unsigned* __restrict__ seg,
                               int E_, int B_){
  __shared__ int hist[MAXB];
  __shared__ int bbase[MAXB];
  for (int i = threadIdx.x; i < B_; i += 256) hist[i] = 0;
  __syncthreads();
  int chunk = (E_ + gridDim.x - 1) / gridDim.x;
  int s = blockIdx.x * chunk;
  int e = s + chunk; if (e > E_) e = E_;
  int is64 = flags[0];
  for (int i = s + (int)threadIdx.x; i < e; i += 256){
    int dst = is64 ? ei[2*E_ + 2*i] : ei[E_ + i];
    atomicAdd(&hist[dst >> BSH], 1);
  }
  __syncthreads();
  for (int i = threadIdx.x; i < B_; i += 256){
    int c = hist[i];
    bbase[i] = c ? atomAddI(&cursor[i], c) : 0;
  }
  __syncthreads();
  for (int i = threadIdx.x; i < B_; i += 256) hist[i] = 0;  // reuse as local offset
  __syncthreads();
  for (int i = s + (int)threadIdx.x; i < e; i += 256){
    int src, dst;
    edge_nodes(ei, E_, is64, i, src, dst);
    int b = dst >> BSH;
    int pos = bbase[b] + atomicAdd(&hist[b], 1);
    seg[pos] = ((unsigned)src << BSH) | (unsigned)(dst & (BSZ-1));
  }
}

// ---------------- bucket finalize: exact per-dst CSR (verified r9) ----------------
__global__ void bucket_finalize(const unsigned* __restrict__ seg,
                                const int* __restrict__ offsets,
                                int* __restrict__ row, int* __restrict__ csr_src,
                                int N_, int B_){
  __shared__ int hist[BSZ];
  __shared__ int sc[BSZ];
  __shared__ int loff[BSZ];
  int b = blockIdx.x;
  int t = threadIdx.x;
  int base = offsets[b], cnt = offsets[b+1] - base;
  if (t < BSZ) hist[t] = 0;
  __syncthreads();
  for (int i = t; i < cnt; i += 256)
    atomicAdd(&hist[seg[base+i] & (BSZ-1)], 1);
  __syncthreads();
  if (t < BSZ) sc[t] = hist[t];
  __syncthreads();
  for (int off = 1; off < BSZ; off <<= 1){
    int tmp = (t < BSZ && t >= off) ? sc[t-off] : 0;
    __syncthreads();
    if (t < BSZ) sc[t] += tmp;
    __syncthreads();
  }
  if (t < BSZ){
    int excl = sc[t] - hist[t];
    loff[t] = excl;
    int node = b*BSZ + t;
    if (node <= N_) row[node] = base + excl;
  }
  if (b == B_-1 && t == 0) row[N_] = offsets[B_];
  __syncthreads();
  for (int i = t; i < cnt; i += 256){
    unsigned en = seg[base+i];
    int dl = en & (BSZ-1);
    int pos = atomicAdd(&loff[dl], 1);
    csr_src[base + pos] = (int)(en >> BSH);
  }
}

// ---------------- fused per-dst gather: 8 lanes/edge, float4/lane ----------------
// Wave per dst. lane = grp*8 + fl: group grp (0..7) owns edges i0 = rs+grp+8t,
// lane fl owns features fl*4..fl*4+3. Dot reduce = 3 width-8 shuffles; leaky =
// max(h, 0.2h). 2 edges per group unrolled (16 outstanding 16B gathers/wave).
// Cross-group combine once per node via 3 width-64 xor shuffles.
__global__ void gat_gather(const int* __restrict__ row, const int* __restrict__ csr_src,
                           const float* __restrict__ xl, const float* __restrict__ xr,
                           const void* __restrict__ att, const void* __restrict__ bias,
                           const int* __restrict__ flags,
                           float* __restrict__ outp, int N_, int do_relu)
{
  int n = blockIdx.x * (blockDim.x >> 6) + (threadIdx.x >> 6);
  if (n >= N_) return;
  int lane = threadIdx.x & 63;
  int fl = lane & 7;           // feature block
  int grp = lane >> 3;         // edge group 0..7
  int f32 = flags[1];
  float4 attk;
  attk.x = ldf(att, f32, fl*4+0);
  attk.y = ldf(att, f32, fl*4+1);
  attk.z = ldf(att, f32, fl*4+2);
  attk.w = ldf(att, f32, fl*4+3);
  float4 xrk = *(const float4*)(xr + (size_t)n*D_HID + fl*4);
  int rs = row[n], re = row[n+1];
  float4 acc = make_float4(0.f, 0.f, 0.f, 0.f);
  float ssum = 0.f;
  for (int i0 = rs + grp; i0 < re; i0 += 16){   // this group's edges: i0, i0+8
    float4 xlv[2];
    int valid[2];
    #pragma unroll
    for (int u = 0; u < 2; ++u){
      int i = i0 + 8*u;
      valid[u] = (i < re);
      int ic = valid[u] ? i : (re - 1);          // clamped: always-legal address
      int src = csr_src[ic];
      xlv[u] = *(const float4*)(xl + (size_t)src*D_HID + fl*4);
    }
    #pragma unroll
    for (int u = 0; u < 2; ++u){
      if (valid[u]){                             // uniform within the 8-lane group
        float4 hh;
        hh.x = xlv[u].x + xrk.x; hh.x = fmaxf(hh.x, NEG*hh.x);
        hh.y = xlv[u].y + xrk.y; hh.y = fmaxf(hh.y, NEG*hh.y);
        hh.z = xlv[u].z + xrk.z; hh.z = fmaxf(hh.z, NEG*hh.z);
        hh.w = xlv[u].w + xrk.w; hh.w = fmaxf(hh.w, NEG*hh.w);
        float p = hh.x*attk.x;
        p = fmaf(hh.y, attk.y, p);
        p = fmaf(hh.z, attk.z, p);
        p = fmaf(hh.w, attk.w, p);
        p += __shfl_xor(p, 1, 8);
        p += __shfl_xor(p, 2, 8);
        p += __shfl_xor(p, 4, 8);
        p = fminf(p, 60.f);                      // safety clamp; real logits |.| <~ 15
        float ev = __expf(p);
        ssum += ev;
        acc.x = fmaf(ev, xlv[u].x, acc.x);
        acc.y = fmaf(ev, xlv[u].y, acc.y);
        acc.z = fmaf(ev, xlv[u].z, acc.z);
        acc.w = fmaf(ev, xlv[u].w, acc.w);
      }
    }
  }
  // combine the 8 groups (lane^8, ^16, ^32 hold the same feature block)
  #pragma unroll
  for (int m = 8; m <= 32; m <<= 1){
    acc.x += __shfl_xor(acc.x, m, 64);
    acc.y += __shfl_xor(acc.y, m, 64);
    acc.z += __shfl_xor(acc.z, m, 64);
    acc.w += __shfl_xor(acc.w, m, 64);
    ssum  += __shfl_xor(ssum,  m, 64);
  }
  if (grp == 0){
    float s = ssum + 1e-16f;
    float4 o;
    o.x = acc.x/s + ldf(bias, f32, fl*4+0);
    o.y = acc.y/s + ldf(bias, f32, fl*4+1);
    o.z = acc.z/s + ldf(bias, f32, fl*4+2);
    o.w = acc.w/s + ldf(bias, f32, fl*4+3);
    if (do_relu){
      o.x = fmaxf(o.x, 0.f); o.y = fmaxf(o.y, 0.f);
      o.z = fmaxf(o.z, 0.f); o.w = fmaxf(o.w, 0.f);
    }
    *(float4*)(outp + (size_t)n*D_HID + fl*4) = o;
  }
}

extern "C" void kernel_launch(void* const* d_in, const int* in_sizes, int n_in,
                              void* d_out, int out_size, void* d_ws, size_t ws_size,
                              hipStream_t stream)
{
  const void* x   = d_in[0];
  const int*  ei  = (const int*)d_in[1];
  const void* W1l = d_in[2];
  const void* W1r = d_in[3];
  const void* att1= d_in[4];
  const void* b1  = d_in[5];
  const void* W2l = d_in[6];
  const void* W2r = d_in[7];
  const void* att2= d_in[8];
  const void* b2  = d_in[9];
  float* out = (float*)d_out;

  int N_ = in_sizes[0] / D_IN;
  int E_ = in_sizes[1] / 2;
  int B_ = (N_ + BSZ - 1) / BSZ;

  char* ws = (char*)d_ws;
  size_t off = 0;
  auto carve = [&](size_t bytes) -> char* {
    char* p = ws + off;
    off += (bytes + 255) & ~(size_t)255;
    return p;
  };
  float*    xl      = (float*)   carve((size_t)N_ * D_HID * 4);
  float*    xr      = (float*)   carve((size_t)N_ * D_HID * 4);
  float*    h       = (float*)   carve((size_t)N_ * D_HID * 4);
  unsigned* seg     = (unsigned*)carve((size_t)E_ * 4);
  int*      csr_src = (int*)     carve((size_t)E_ * 4);
  int*      row     = (int*)     carve((size_t)(N_ + 1) * 4);
  int*      offsets = (int*)     carve((size_t)(MAXB + 1) * 4);
  int*      gcnt    = (int*)     carve((size_t)MAXB * 4);
  int*      cursor  = (int*)     carve((size_t)MAXB * 4);
  int*      flags   = (int*)     carve(256);
  uint4*    whi1    = (uint4*)   carve((size_t)4 * 4 * 64 * 16);  // K=128
  uint4*    wlo1    = (uint4*)   carve((size_t)4 * 4 * 64 * 16);
  uint4*    whi2    = (uint4*)   carve((size_t)4 * 1 * 64 * 16);  // K=32
  uint4*    wlo2    = (uint4*)   carve((size_t)4 * 1 * 64 * 16);

  const int tpb = 256;
  int gW = (N_ + 3) / 4;                    // wave-per-dst grid (4 waves/block)
  int tiles = (N_ + 15) / 16;
  int gT = (tiles + 3) / 4;                 // mfma grid (4 waves/block)

  detect_flags<<<1, 256, 0, stream>>>(ei, (const u16*)x, flags);

  // ---- W fragments ----
  prep_wfrag<<<4, 256, 0, stream>>>(W1l, W1r, flags, D_IN, whi1, wlo1);
  prep_wfrag<<<1, 256, 0, stream>>>(W2l, W2r, flags, D_HID, whi2, wlo2);

  // ---- CSR build (shared by both layers) ----
  hipMemsetAsync(gcnt, 0, (size_t)MAXB * 4, stream);
  bucket_count<<<256, tpb, 0, stream>>>(ei, flags, gcnt, E_, B_);
  scan_buckets<<<1, 1024, 0, stream>>>(gcnt, offsets, cursor, B_);
  bucket_scatter<<<256, tpb, 0, stream>>>(ei, flags, cursor, seg, E_, B_);
  bucket_finalize<<<B_, tpb, 0, stream>>>(seg, offsets, row, csr_src, N_, B_);

  // ---- layer 1 ----
  mfma_gemm<D_IN><<<gT, tpb, 0, stream>>>(x, whi1, wlo1, flags, 0, xl, xr, N_);
  gat_gather<<<gW, tpb, 0, stream>>>(row, csr_src, xl, xr, att1, b1, flags, h, N_, 1);

  // ---- layer 2 ----
  mfma_gemm<D_HID><<<gT, tpb, 0, stream>>>(h, whi2, wlo2, flags, 1, xl, xr, N_);
  gat_gather<<<gW, tpb, 0, stream>>>(row, csr_src, xl, xr, att2, b2, flags, out, N_, 0);
}